// Round 7
// baseline (88.500 us; speedup 1.0000x reference)
//
#include <hip/hip_runtime.h>

// SRM fused kernel, M=4, S=2, B=2, C=128, H=W=512 — LDS-free version.
//
// Verified algebra (rounds 1/3-6 passed): per window (P,Q) the 16 gather
// coords equal the 16 scatter coords: rows {4P-2,4P-1,4P+4,4P+5}, cols
// {4Q-2,4Q-1,4Q+4,4Q+5}, clamped at edges; coord map is a bijection.
// Column structure per row: window Q reads/writes floats {4Q-2,4Q-1}
// (hi-half of 16B chunk Q-1) and {4Q+4,4Q+5} (lo-half of chunk Q+1).
//
// Thread (bc,P,c): loads its OWN 16B-aligned chunk c of the window's 4 rows
// (lane-dense coalesced), neighbor halves arrive via __shfl_up/down(1);
// output chunk c = [window(c-1) pair1' | window(c+1) pair0'] is assembled
// by the mirrored shuffles and NT-stored. Wave-edge lanes (c=0/63/64/127)
// use clamp identities or 8B global patches (disjoint from all f4 stores).
// No LDS, no barriers: global->VGPR->global, each byte touched once.

typedef float f4 __attribute__((ext_vector_type(4)));
typedef float f2 __attribute__((ext_vector_type(2)));

__global__ __launch_bounds__(256) void srm_kernel(
    const float* __restrict__ x, const float* __restrict__ fw,
    const float* __restrict__ fb, float* __restrict__ out)
{
    const int t    = threadIdx.x;
    const int blk  = blockIdx.x;
    const int c    = t & 127;                       // 16B chunk / window col
    const int P    = ((blk & 63) << 1) | (t >> 7);  // window row
    const int bc   = blk >> 6;                      // b*C + c in [0,256)
    const int lane = t & 63;

    const float* xp = x   + (size_t)bc * (512 * 512);
    float*       op = out + (size_t)bc * (512 * 512);

    const int r0 = (P == 0)   ? 0   : 4 * P - 2;
    const int r2 = (P == 127) ? 510 : 4 * P + 4;
    const int rows[4] = {r0, r0 + 1, r2, r2 + 1};

    // ---- load own chunk of each window row (lane-dense, 16B aligned)
    f4 A[4];
#pragma unroll
    for (int j = 0; j < 4; ++j)
        A[j] = *reinterpret_cast<const f4*>(xp + rows[j] * 512 + 4 * c);

    // ---- wave-edge patch loads (2 lanes per wave; L1/L2 hits)
    const bool lane0 = (lane == 0), lane63 = (lane == 63);
    f2 E[4];
    if (lane0 && c != 0) {          // c == 64: pair0 = floats {254,255}
#pragma unroll
        for (int j = 0; j < 4; ++j)
            E[j] = *reinterpret_cast<const f2*>(xp + rows[j] * 512 + 4 * c - 2);
    }
    if (lane63 && c != 127) {       // c == 63: pair1 = floats {256,257}
#pragma unroll
        for (int j = 0; j < 4; ++j)
            E[j] = *reinterpret_cast<const f2*>(xp + rows[j] * 512 + 4 * c + 4);
    }

    // ---- gather via shuffles: pair0 = hi-half of chunk c-1,
    //                           pair1 = lo-half of chunk c+1
    float v[16];
#pragma unroll
    for (int j = 0; j < 4; ++j) {
        float p0x = __shfl_up(A[j].z, 1);
        float p0y = __shfl_up(A[j].w, 1);
        float p1x = __shfl_down(A[j].x, 1);
        float p1y = __shfl_down(A[j].y, 1);
        if (lane0) {
            if (c == 0) { p0x = A[j].x; p0y = A[j].y; }   // clamp {0,1}
            else        { p0x = E[j].x; p0y = E[j].y; }
        }
        if (lane63) {
            if (c == 127) { p1x = A[j].z; p1y = A[j].w; } // clamp {510,511}
            else          { p1x = E[j].x; p1y = E[j].y; }
        }
        v[4 * j + 0] = p0x;  v[4 * j + 1] = p0y;
        v[4 * j + 2] = p1x;  v[4 * j + 3] = p1y;
    }

    // ---- 16x16 matvec; weights/bias via wave-uniform (scalar) loads
    float u[16];
#pragma unroll
    for (int o = 0; o < 16; ++o) {
        float acc = fb[o];
#pragma unroll
        for (int f = 0; f < 16; ++f) acc += fw[16 * o + f] * v[f];
        u[o] = acc;
    }

    // ---- scatter: assemble own output chunk via mirrored shuffles
#pragma unroll
    for (int j = 0; j < 4; ++j) {
        float lox = __shfl_up(u[4 * j + 2], 1);     // window(c-1) pair1'
        float loy = __shfl_up(u[4 * j + 3], 1);
        float hix = __shfl_down(u[4 * j + 0], 1);   // window(c+1) pair0'
        float hiy = __shfl_down(u[4 * j + 1], 1);
        float* rp = op + rows[j] * 512;
        bool full = true;
        if (lane0) {
            if (c == 0) { lox = u[4 * j + 0]; loy = u[4 * j + 1]; }  // clamp
            else {  // c==64: own pair0' -> chunk63 hi; then own chunk hi only
                __builtin_nontemporal_store(
                    f2{u[4 * j + 0], u[4 * j + 1]},
                    reinterpret_cast<f2*>(rp + 4 * c - 2));
                __builtin_nontemporal_store(
                    f2{hix, hiy}, reinterpret_cast<f2*>(rp + 4 * c + 2));
                full = false;
            }
        }
        if (lane63) {
            if (c == 127) { hix = u[4 * j + 2]; hiy = u[4 * j + 3]; } // clamp
            else {  // c==63: own chunk lo; own pair1' -> chunk64 lo
                __builtin_nontemporal_store(
                    f2{lox, loy}, reinterpret_cast<f2*>(rp + 4 * c));
                __builtin_nontemporal_store(
                    f2{u[4 * j + 2], u[4 * j + 3]},
                    reinterpret_cast<f2*>(rp + 4 * c + 4));
                full = false;
            }
        }
        if (full)
            __builtin_nontemporal_store(
                f4{lox, loy, hix, hiy}, reinterpret_cast<f4*>(rp + 4 * c));
    }
}

extern "C" void kernel_launch(void* const* d_in, const int* in_sizes, int n_in,
                              void* d_out, int out_size, void* d_ws, size_t ws_size,
                              hipStream_t stream) {
    const float* x  = (const float*)d_in[0];
    const float* fw = (const float*)d_in[1];
    const float* fb = (const float*)d_in[2];
    float* out = (float*)d_out;

    // threads = bc(256) * P(128) * c(128) = 4,194,304 -> 16384 blocks
    srm_kernel<<<16384, 256, 0, stream>>>(x, fw, fb, out);
}